// Round 1
// baseline (1364.256 us; speedup 1.0000x reference)
//
#include <hip/hip_runtime.h>
#include <cstdint>
#include <cstddef>

// ---------------------------------------------------------------------------
// CADGroupingGNN: 3x GCNConv(128->128) + MLP classifier, N=50000, E=800000.
// Graph normalization (deg/dinv/norm) computed once, reused by all 3 layers.
// Aggregation via float atomics (round 0: correctness-first).
// ---------------------------------------------------------------------------

__global__ __launch_bounds__(256) void k_init_deg(float* __restrict__ deg, int n) {
  int i = blockIdx.x * 256 + threadIdx.x;
  if (i < n) deg[i] = 1.0f;   // self-loop weight 1
}

__global__ __launch_bounds__(256) void k_edge_weight(
    const int* __restrict__ attr, const float* __restrict__ emb,
    const int* __restrict__ col, float* __restrict__ ew,
    float* __restrict__ deg, int E) {
  int e = blockIdx.x * 256 + threadIdx.x;
  if (e < E) {
    float w = emb[attr[e]];
    ew[e] = w;
    atomicAdd(&deg[col[e]], w);
  }
}

__global__ __launch_bounds__(256) void k_dinv(
    float* __restrict__ deg, float* __restrict__ snorm, int n) {
  int i = blockIdx.x * 256 + threadIdx.x;
  if (i < n) {
    float d = deg[i];
    float v = d > 0.f ? rsqrtf(d) : 0.f;
    deg[i] = v;          // deg becomes dinv in place
    snorm[i] = v * v;    // self-loop norm
  }
}

__global__ __launch_bounds__(256) void k_norm(
    const float* __restrict__ ew, const float* __restrict__ dinv,
    const int* __restrict__ row, const int* __restrict__ col,
    float* __restrict__ nrm, int E) {
  int e = blockIdx.x * 256 + threadIdx.x;
  if (e < E) nrm[e] = dinv[row[e]] * ew[e] * dinv[col[e]];
}

// out[i][j] = b[j] + snorm[i] * h[i][j]   (self-loop term + bias)
__global__ __launch_bounds__(256) void k_agg_init(
    const float* __restrict__ h, const float* __restrict__ snorm,
    const float* __restrict__ b, float* __restrict__ out, int total) {
  int idx = blockIdx.x * 256 + threadIdx.x;
  if (idx < total) {
    int i = idx >> 7, j = idx & 127;
    out[idx] = b[j] + snorm[i] * h[idx];
  }
}

// out[col[e]][j] += norm[e] * h[row[e]][j]  for all e, j  (128 lanes per edge)
__global__ __launch_bounds__(256) void k_agg_edge(
    const float* __restrict__ h, const float* __restrict__ nrm,
    const int* __restrict__ row, const int* __restrict__ col,
    float* __restrict__ out, int E) {
  int idx = blockIdx.x * 256 + threadIdx.x;
  int e = idx >> 7;
  if (e < E) {
    int j = idx & 127;
    float v = nrm[e];
    int r = row[e], c = col[e];
    atomicAdd(out + (((size_t)c) << 7) + j, v * h[(((size_t)r) << 7) + j]);
  }
}

// GEMM: out[M x HOUT] = act( f(A[M x 128]) @ W[128 x HOUT] + bias )
// f = optional relu on input; ACT: 0 none, 1 relu, 2 sigmoid.
// Block: 256 threads, 64 rows. W staged fully in LDS.
template <int HOUT, int ACT, bool RELU_IN>
__global__ __launch_bounds__(256) void k_gemm(
    const float* __restrict__ A, const float* __restrict__ W,
    const float* __restrict__ bias, float* __restrict__ out, int M) {
  constexpr int CG = HOUT / 4;     // thread column-groups (float4 wide)
  constexpr int TM = CG / 4;       // rows per thread (8 for HOUT=128, 4 for 64)
  __shared__ float Ws[128 * HOUT];
  __shared__ float Xs[64][132];    // pad 128->132 keeps float4 LDS alignment

  const int t = threadIdx.x;
  const int m0 = blockIdx.x * 64;

  for (int i = t; i < 128 * HOUT / 4; i += 256)
    ((float4*)Ws)[i] = ((const float4*)W)[i];

  for (int i = t; i < 64 * 32; i += 256) {
    int r = i >> 5, c4 = i & 31;
    int gr = m0 + r;
    float4 v = make_float4(0.f, 0.f, 0.f, 0.f);
    if (gr < M) v = ((const float4*)A)[(size_t)gr * 32 + c4];
    if (RELU_IN) {
      v.x = fmaxf(v.x, 0.f); v.y = fmaxf(v.y, 0.f);
      v.z = fmaxf(v.z, 0.f); v.w = fmaxf(v.w, 0.f);
    }
    *(float4*)&Xs[r][c4 * 4] = v;
  }
  __syncthreads();

  const int tc = t % CG;
  const int tr = t / CG;
  float acc[TM][4];
#pragma unroll
  for (int i = 0; i < TM; ++i)
    acc[i][0] = acc[i][1] = acc[i][2] = acc[i][3] = 0.f;

#pragma unroll 4
  for (int k = 0; k < 128; ++k) {
    float4 wv = *(const float4*)&Ws[k * HOUT + tc * 4];
#pragma unroll
    for (int i = 0; i < TM; ++i) {
      float a = Xs[tr * TM + i][k];
      acc[i][0] = fmaf(a, wv.x, acc[i][0]);
      acc[i][1] = fmaf(a, wv.y, acc[i][1]);
      acc[i][2] = fmaf(a, wv.z, acc[i][2]);
      acc[i][3] = fmaf(a, wv.w, acc[i][3]);
    }
  }

#pragma unroll
  for (int i = 0; i < TM; ++i) {
    int gr = m0 + tr * TM + i;
    if (gr >= M) continue;
    float4 v = make_float4(acc[i][0], acc[i][1], acc[i][2], acc[i][3]);
    if (bias) {
      const float4 bv = *(const float4*)&bias[tc * 4];
      v.x += bv.x; v.y += bv.y; v.z += bv.z; v.w += bv.w;
    }
    if (ACT == 1) {
      v.x = fmaxf(v.x, 0.f); v.y = fmaxf(v.y, 0.f);
      v.z = fmaxf(v.z, 0.f); v.w = fmaxf(v.w, 0.f);
    } else if (ACT == 2) {
      v.x = 1.f / (1.f + __expf(-v.x));
      v.y = 1.f / (1.f + __expf(-v.y));
      v.z = 1.f / (1.f + __expf(-v.z));
      v.w = 1.f / (1.f + __expf(-v.w));
    }
    ((float4*)out)[(size_t)gr * CG + tc] = v;
  }
}

extern "C" void kernel_launch(void* const* d_in, const int* in_sizes, int n_in,
                              void* d_out, int out_size, void* d_ws, size_t ws_size,
                              hipStream_t stream) {
  const float* x        = (const float*)d_in[0];
  const float* edge_emb = (const float*)d_in[1];
  const float* W1 = (const float*)d_in[2];  const float* b1 = (const float*)d_in[3];
  const float* W2 = (const float*)d_in[4];  const float* b2 = (const float*)d_in[5];
  const float* W3 = (const float*)d_in[6];  const float* b3 = (const float*)d_in[7];
  const float* cW1 = (const float*)d_in[8]; const float* cb1 = (const float*)d_in[9];
  const float* cW2 = (const float*)d_in[10]; const float* cb2 = (const float*)d_in[11];
  const int* eidx  = (const int*)d_in[12];
  const int* eattr = (const int*)d_in[13];

  const int N = in_sizes[0] / 128;
  const int E = in_sizes[13];
  const int* row = eidx;        // edge_index[0] = source
  const int* col = eidx + E;    // edge_index[1] = target

  float* out = (float*)d_out;

  // workspace layout (all float, 16B-aligned offsets)
  float* deg   = (float*)d_ws;            // N   (becomes dinv in place)
  float* snorm = deg + N;                 // N
  float* ew    = snorm + N;               // E
  float* nrm   = ew + E;                  // E
  float* bufA  = nrm + E;                 // N*128
  float* bufB  = bufA + (size_t)N * 128;  // N*128

  const int gN  = (N + 255) / 256;
  const int gE  = (E + 255) / 256;
  const int gG  = (N + 63) / 64;
  const int gNH = (N * 128 + 255) / 256;
  const long long totE = (long long)E * 128;
  const int gEH = (int)((totE + 255) / 256);

  // graph normalization (shared across all 3 GCN layers)
  k_init_deg<<<gN, 256, 0, stream>>>(deg, N);
  k_edge_weight<<<gE, 256, 0, stream>>>(eattr, edge_emb, col, ew, deg, E);
  k_dinv<<<gN, 256, 0, stream>>>(deg, snorm, N);
  k_norm<<<gE, 256, 0, stream>>>(ew, deg, row, col, nrm, E);

  // layer 1: h1 = x @ W1 ; bufB = b1 + snorm*h1 + scatter
  k_gemm<128, 0, false><<<gG, 256, 0, stream>>>(x, W1, nullptr, bufA, N);
  k_agg_init<<<gNH, 256, 0, stream>>>(bufA, snorm, b1, bufB, N * 128);
  k_agg_edge<<<gEH, 256, 0, stream>>>(bufA, nrm, row, col, bufB, E);

  // layer 2 (relu fused into GEMM input load)
  k_gemm<128, 0, true><<<gG, 256, 0, stream>>>(bufB, W2, nullptr, bufA, N);
  k_agg_init<<<gNH, 256, 0, stream>>>(bufA, snorm, b2, bufB, N * 128);
  k_agg_edge<<<gEH, 256, 0, stream>>>(bufA, nrm, row, col, bufB, E);

  // layer 3
  k_gemm<128, 0, true><<<gG, 256, 0, stream>>>(bufB, W3, nullptr, bufA, N);
  k_agg_init<<<gNH, 256, 0, stream>>>(bufA, snorm, b3, bufB, N * 128);
  k_agg_edge<<<gEH, 256, 0, stream>>>(bufA, nrm, row, col, bufB, E);

  // classifier: relu(relu(bufB) @ cW1 + cb1) -> bufA ; sigmoid(bufA @ cW2 + cb2) -> out
  k_gemm<128, 1, true><<<gG, 256, 0, stream>>>(bufB, cW1, cb1, bufA, N);
  k_gemm<64, 2, false><<<gG, 256, 0, stream>>>(bufA, cW2, cb2, out, N);
}

// Round 2
// 595.626 us; speedup vs baseline: 2.2905x; 2.2905x over previous
//
#include <hip/hip_runtime.h>
#include <cstdint>
#include <cstddef>

// ---------------------------------------------------------------------------
// CADGroupingGNN: 3x GCNConv(128->128) + MLP classifier, N=50000, E=800000.
// Round 1: replace float-atomic scatter aggregation (74% of runtime, 400 MB
// of HBM atomic writes per layer) with a per-launch CSR build + per-node
// register gather-reduce (one coalesced 512B write per node, no float atomics).
// ---------------------------------------------------------------------------

__global__ __launch_bounds__(256) void k_init(float* __restrict__ deg,
                                              int* __restrict__ cnt, int n) {
  int i = blockIdx.x * 256 + threadIdx.x;
  if (i < n) { deg[i] = 1.0f; cnt[i] = 0; }   // self-loop weight 1
}

// degree accumulation + in-degree histogram in one pass
__global__ __launch_bounds__(256) void k_deg_hist(
    const int* __restrict__ attr, const float* __restrict__ emb,
    const int* __restrict__ col, float* __restrict__ deg,
    int* __restrict__ cnt, int E) {
  int e = blockIdx.x * 256 + threadIdx.x;
  if (e < E) {
    int c = col[e];
    atomicAdd(&deg[c], emb[attr[e]]);
    atomicAdd(&cnt[c], 1);
  }
}

__global__ __launch_bounds__(256) void k_dinv(
    float* __restrict__ deg, float* __restrict__ snorm, int n) {
  int i = blockIdx.x * 256 + threadIdx.x;
  if (i < n) {
    float d = deg[i];
    float v = d > 0.f ? rsqrtf(d) : 0.f;
    deg[i] = v;          // deg becomes dinv in place
    snorm[i] = v * v;    // self-loop norm
  }
}

// ---- exclusive scan of cnt[] over N elements (3 kernels) ----
__global__ __launch_bounds__(256) void k_scan1(
    const int* __restrict__ cnt, int* __restrict__ start,
    int* __restrict__ bsum, int n) {
  __shared__ int s[256];
  int t = threadIdx.x, idx = blockIdx.x * 256 + t;
  s[t] = (idx < n) ? cnt[idx] : 0;
  for (int d = 1; d < 256; d <<= 1) {
    __syncthreads();
    int x = (t >= d) ? s[t - d] : 0;
    __syncthreads();
    s[t] += x;
  }
  __syncthreads();
  if (idx < n) start[idx + 1] = s[t];          // inclusive, per-block
  if (t == 255) bsum[blockIdx.x] = s[255];
}

__global__ __launch_bounds__(256) void k_scan2(int* __restrict__ bsum, int nb) {
  __shared__ int s[256];
  int t = threadIdx.x;
  s[t] = (t < nb) ? bsum[t] : 0;
  for (int d = 1; d < 256; d <<= 1) {
    __syncthreads();
    int x = (t >= d) ? s[t - d] : 0;
    __syncthreads();
    s[t] += x;
  }
  __syncthreads();
  if (t < nb) bsum[t] = s[t];                  // inclusive block sums
}

__global__ __launch_bounds__(256) void k_scan3(
    const int* __restrict__ cnt, int* __restrict__ start,
    const int* __restrict__ bsum, int* __restrict__ cursor, int n) {
  int b = blockIdx.x, idx = b * 256 + threadIdx.x;
  if (idx < n) {
    int off = (b > 0) ? bsum[b - 1] : 0;
    int incl = start[idx + 1] + off;
    start[idx + 1] = incl;
    cursor[idx] = incl - cnt[idx];             // exclusive
    if (idx == 0) start[0] = 0;
  }
}

// bucket-fill sorted-by-target edge list; per-edge norm computed inline
__global__ __launch_bounds__(256) void k_fill(
    const int* __restrict__ attr, const float* __restrict__ emb,
    const int* __restrict__ row, const int* __restrict__ col,
    const float* __restrict__ dinv, int* __restrict__ cursor,
    int* __restrict__ srcs, float* __restrict__ wts, int E) {
  int e = blockIdx.x * 256 + threadIdx.x;
  if (e < E) {
    int r = row[e], c = col[e];
    int p = atomicAdd(&cursor[c], 1);
    srcs[p] = r;
    wts[p] = dinv[r] * emb[attr[e]] * dinv[c];
  }
}

// out[i][:] = bias + snorm[i]*h[i][:] + sum_e wts[e]*h[srcs[e]][:]
// 32 lanes per node, float4 per lane (128 channels).
__global__ __launch_bounds__(256) void k_agg_csr(
    const float* __restrict__ h, const int* __restrict__ start,
    const int* __restrict__ srcs, const float* __restrict__ wts,
    const float* __restrict__ snorm, const float* __restrict__ bias,
    float* __restrict__ out, int n) {
  int tid = blockIdx.x * 256 + threadIdx.x;
  int i = tid >> 5;
  if (i >= n) return;
  int lane = tid & 31;
  const float4* h4 = (const float4*)h;
  float4 acc = ((const float4*)bias)[lane];
  float sn = snorm[i];
  float4 hv = h4[(size_t)i * 32 + lane];
  acc.x += sn * hv.x; acc.y += sn * hv.y;
  acc.z += sn * hv.z; acc.w += sn * hv.w;

  int e = start[i], eend = start[i + 1];
  for (; e + 4 <= eend; e += 4) {
    int r0 = srcs[e], r1 = srcs[e + 1], r2 = srcs[e + 2], r3 = srcs[e + 3];
    float w0 = wts[e], w1 = wts[e + 1], w2 = wts[e + 2], w3 = wts[e + 3];
    float4 v0 = h4[(size_t)r0 * 32 + lane];
    float4 v1 = h4[(size_t)r1 * 32 + lane];
    float4 v2 = h4[(size_t)r2 * 32 + lane];
    float4 v3 = h4[(size_t)r3 * 32 + lane];
    acc.x = fmaf(w0, v0.x, acc.x); acc.y = fmaf(w0, v0.y, acc.y);
    acc.z = fmaf(w0, v0.z, acc.z); acc.w = fmaf(w0, v0.w, acc.w);
    acc.x = fmaf(w1, v1.x, acc.x); acc.y = fmaf(w1, v1.y, acc.y);
    acc.z = fmaf(w1, v1.z, acc.z); acc.w = fmaf(w1, v1.w, acc.w);
    acc.x = fmaf(w2, v2.x, acc.x); acc.y = fmaf(w2, v2.y, acc.y);
    acc.z = fmaf(w2, v2.z, acc.z); acc.w = fmaf(w2, v2.w, acc.w);
    acc.x = fmaf(w3, v3.x, acc.x); acc.y = fmaf(w3, v3.y, acc.y);
    acc.z = fmaf(w3, v3.z, acc.z); acc.w = fmaf(w3, v3.w, acc.w);
  }
  for (; e < eend; ++e) {
    float w = wts[e];
    float4 v = h4[(size_t)srcs[e] * 32 + lane];
    acc.x = fmaf(w, v.x, acc.x); acc.y = fmaf(w, v.y, acc.y);
    acc.z = fmaf(w, v.z, acc.z); acc.w = fmaf(w, v.w, acc.w);
  }
  ((float4*)out)[(size_t)i * 32 + lane] = acc;
}

// GEMM: out[M x HOUT] = act( f(A[M x 128]) @ W[128 x HOUT] + bias )
// f = optional relu on input; ACT: 0 none, 1 relu, 2 sigmoid.
template <int HOUT, int ACT, bool RELU_IN>
__global__ __launch_bounds__(256) void k_gemm(
    const float* __restrict__ A, const float* __restrict__ W,
    const float* __restrict__ bias, float* __restrict__ out, int M) {
  constexpr int CG = HOUT / 4;     // thread column-groups (float4 wide)
  constexpr int TM = CG / 4;       // rows per thread
  __shared__ float Ws[128 * HOUT];
  __shared__ float Xs[64][132];

  const int t = threadIdx.x;
  const int m0 = blockIdx.x * 64;

  for (int i = t; i < 128 * HOUT / 4; i += 256)
    ((float4*)Ws)[i] = ((const float4*)W)[i];

  for (int i = t; i < 64 * 32; i += 256) {
    int r = i >> 5, c4 = i & 31;
    int gr = m0 + r;
    float4 v = make_float4(0.f, 0.f, 0.f, 0.f);
    if (gr < M) v = ((const float4*)A)[(size_t)gr * 32 + c4];
    if (RELU_IN) {
      v.x = fmaxf(v.x, 0.f); v.y = fmaxf(v.y, 0.f);
      v.z = fmaxf(v.z, 0.f); v.w = fmaxf(v.w, 0.f);
    }
    *(float4*)&Xs[r][c4 * 4] = v;
  }
  __syncthreads();

  const int tc = t % CG;
  const int tr = t / CG;
  float acc[TM][4];
#pragma unroll
  for (int i = 0; i < TM; ++i)
    acc[i][0] = acc[i][1] = acc[i][2] = acc[i][3] = 0.f;

#pragma unroll 4
  for (int k = 0; k < 128; ++k) {
    float4 wv = *(const float4*)&Ws[k * HOUT + tc * 4];
#pragma unroll
    for (int i = 0; i < TM; ++i) {
      float a = Xs[tr * TM + i][k];
      acc[i][0] = fmaf(a, wv.x, acc[i][0]);
      acc[i][1] = fmaf(a, wv.y, acc[i][1]);
      acc[i][2] = fmaf(a, wv.z, acc[i][2]);
      acc[i][3] = fmaf(a, wv.w, acc[i][3]);
    }
  }

#pragma unroll
  for (int i = 0; i < TM; ++i) {
    int gr = m0 + tr * TM + i;
    if (gr >= M) continue;
    float4 v = make_float4(acc[i][0], acc[i][1], acc[i][2], acc[i][3]);
    if (bias) {
      const float4 bv = *(const float4*)&bias[tc * 4];
      v.x += bv.x; v.y += bv.y; v.z += bv.z; v.w += bv.w;
    }
    if (ACT == 1) {
      v.x = fmaxf(v.x, 0.f); v.y = fmaxf(v.y, 0.f);
      v.z = fmaxf(v.z, 0.f); v.w = fmaxf(v.w, 0.f);
    } else if (ACT == 2) {
      v.x = 1.f / (1.f + __expf(-v.x));
      v.y = 1.f / (1.f + __expf(-v.y));
      v.z = 1.f / (1.f + __expf(-v.z));
      v.w = 1.f / (1.f + __expf(-v.w));
    }
    ((float4*)out)[(size_t)gr * CG + tc] = v;
  }
}

extern "C" void kernel_launch(void* const* d_in, const int* in_sizes, int n_in,
                              void* d_out, int out_size, void* d_ws, size_t ws_size,
                              hipStream_t stream) {
  const float* x        = (const float*)d_in[0];
  const float* edge_emb = (const float*)d_in[1];
  const float* W1 = (const float*)d_in[2];  const float* b1 = (const float*)d_in[3];
  const float* W2 = (const float*)d_in[4];  const float* b2 = (const float*)d_in[5];
  const float* W3 = (const float*)d_in[6];  const float* b3 = (const float*)d_in[7];
  const float* cW1 = (const float*)d_in[8]; const float* cb1 = (const float*)d_in[9];
  const float* cW2 = (const float*)d_in[10]; const float* cb2 = (const float*)d_in[11];
  const int* eidx  = (const int*)d_in[12];
  const int* eattr = (const int*)d_in[13];

  const int N = in_sizes[0] / 128;
  const int E = in_sizes[13];
  const int* row = eidx;        // edge_index[0] = source
  const int* col = eidx + E;    // edge_index[1] = target

  float* out = (float*)d_out;

  // workspace layout, 16B-aligned slots (element counts rounded to x4)
  size_t off = 0;
  auto alloc4 = [&](size_t n) { size_t o = off; off += (n + 3) & ~(size_t)3; return o; };
  float* wsf = (float*)d_ws;
  int*   wsi = (int*)d_ws;

  float* deg    = wsf + alloc4(N);
  float* snorm  = wsf + alloc4(N);
  int*   cnt    = wsi + alloc4(N);
  int*   start  = wsi + alloc4(N + 1);
  int*   cursor = wsi + alloc4(N);
  int*   bsum   = wsi + alloc4(256);
  int*   srcs   = wsi + alloc4(E);
  float* wts    = wsf + alloc4(E);
  float* bufA   = wsf + alloc4((size_t)N * 128);
  float* bufB   = wsf + alloc4((size_t)N * 128);

  const int gN  = (N + 255) / 256;
  const int gE  = (E + 255) / 256;
  const int gG  = (N + 63) / 64;
  const int gA  = (N * 32 + 255) / 256;
  const int nb  = gN;  // scan blocks

  // ---- graph preprocessing (once, reused by all 3 layers) ----
  k_init<<<gN, 256, 0, stream>>>(deg, cnt, N);
  k_deg_hist<<<gE, 256, 0, stream>>>(eattr, edge_emb, col, deg, cnt, E);
  k_dinv<<<gN, 256, 0, stream>>>(deg, snorm, N);
  k_scan1<<<nb, 256, 0, stream>>>(cnt, start, bsum, N);
  k_scan2<<<1, 256, 0, stream>>>(bsum, nb);
  k_scan3<<<nb, 256, 0, stream>>>(cnt, start, bsum, cursor, N);
  k_fill<<<gE, 256, 0, stream>>>(eattr, edge_emb, row, col, deg, cursor,
                                 srcs, wts, E);

  // ---- layer 1 ----
  k_gemm<128, 0, false><<<gG, 256, 0, stream>>>(x, W1, nullptr, bufA, N);
  k_agg_csr<<<gA, 256, 0, stream>>>(bufA, start, srcs, wts, snorm, b1, bufB, N);
  // ---- layer 2 (relu fused into GEMM input load) ----
  k_gemm<128, 0, true><<<gG, 256, 0, stream>>>(bufB, W2, nullptr, bufA, N);
  k_agg_csr<<<gA, 256, 0, stream>>>(bufA, start, srcs, wts, snorm, b2, bufB, N);
  // ---- layer 3 ----
  k_gemm<128, 0, true><<<gG, 256, 0, stream>>>(bufB, W3, nullptr, bufA, N);
  k_agg_csr<<<gA, 256, 0, stream>>>(bufA, start, srcs, wts, snorm, b3, bufB, N);

  // ---- classifier ----
  k_gemm<128, 1, true><<<gG, 256, 0, stream>>>(bufB, cW1, cb1, bufA, N);
  k_gemm<64, 2, false><<<gG, 256, 0, stream>>>(bufA, cW2, cb2, out, N);
}

// Round 3
// 547.177 us; speedup vs baseline: 2.4933x; 1.0885x over previous
//
#include <hip/hip_runtime.h>
#include <cstdint>
#include <cstddef>

// ---------------------------------------------------------------------------
// CADGroupingGNN: 3x GCNConv(128->128) + MLP classifier, N=50000, E=800000.
// Round 2: preprocessing de-atomic-ification. Single int atomic per edge
// (histogram, old value kept as in-bucket rank), atomic-free bucket fill,
// deterministic per-node degree sum + in-place weight normalization.
// ---------------------------------------------------------------------------

__global__ __launch_bounds__(256) void k_init(int* __restrict__ cnt, int n) {
  int i = blockIdx.x * 256 + threadIdx.x;
  if (i < n) cnt[i] = 0;
}

// in-degree histogram; returned old count = edge's slot within its bucket
__global__ __launch_bounds__(256) void k_hist(
    const int* __restrict__ col, int* __restrict__ cnt,
    int* __restrict__ rank, int E) {
  int e = blockIdx.x * 256 + threadIdx.x;
  if (e < E) rank[e] = atomicAdd(&cnt[col[e]], 1);
}

// ---- exclusive scan of cnt[] over N elements (3 kernels) ----
__global__ __launch_bounds__(256) void k_scan1(
    const int* __restrict__ cnt, int* __restrict__ start,
    int* __restrict__ bsum, int n) {
  __shared__ int s[256];
  int t = threadIdx.x, idx = blockIdx.x * 256 + t;
  s[t] = (idx < n) ? cnt[idx] : 0;
  for (int d = 1; d < 256; d <<= 1) {
    __syncthreads();
    int x = (t >= d) ? s[t - d] : 0;
    __syncthreads();
    s[t] += x;
  }
  __syncthreads();
  if (idx < n) start[idx + 1] = s[t];          // inclusive, per-block
  if (t == 255) bsum[blockIdx.x] = s[255];
}

__global__ __launch_bounds__(256) void k_scan2(int* __restrict__ bsum, int nb) {
  __shared__ int s[256];
  int t = threadIdx.x;
  s[t] = (t < nb) ? bsum[t] : 0;
  for (int d = 1; d < 256; d <<= 1) {
    __syncthreads();
    int x = (t >= d) ? s[t - d] : 0;
    __syncthreads();
    s[t] += x;
  }
  __syncthreads();
  if (t < nb) bsum[t] = s[t];                  // inclusive block sums
}

__global__ __launch_bounds__(256) void k_scan3(
    int* __restrict__ start, const int* __restrict__ bsum, int n) {
  int b = blockIdx.x, idx = b * 256 + threadIdx.x;
  if (idx < n) {
    int off = (b > 0) ? bsum[b - 1] : 0;
    start[idx + 1] += off;
    if (idx == 0) start[0] = 0;
  }
}

// atomic-free bucket fill: p = start[col] + rank
__global__ __launch_bounds__(256) void k_fill(
    const int* __restrict__ attr, const float* __restrict__ emb,
    const int* __restrict__ row, const int* __restrict__ col,
    const int* __restrict__ rank, const int* __restrict__ start,
    int* __restrict__ srcs, float* __restrict__ ew_s, int E) {
  int e = blockIdx.x * 256 + threadIdx.x;
  if (e < E) {
    int p = start[col[e]] + rank[e];
    srcs[p] = row[e];
    ew_s[p] = emb[attr[e]];
  }
}

// per-node deterministic degree sum -> dinv (stored in deg), snorm
__global__ __launch_bounds__(256) void k_deg_csr(
    const int* __restrict__ start, const float* __restrict__ ew_s,
    float* __restrict__ dinv, float* __restrict__ snorm, int n) {
  int i = blockIdx.x * 256 + threadIdx.x;
  if (i >= n) return;
  int s = start[i], e = start[i + 1];
  float d = 1.0f;                              // self-loop weight
  for (int p = s; p < e; ++p) d += ew_s[p];
  float v = d > 0.f ? rsqrtf(d) : 0.f;
  dinv[i] = v;
  snorm[i] = v * v;
}

// per-node in-place weight normalization: ew_s[p] *= dinv[src]*dinv[i]
__global__ __launch_bounds__(256) void k_wts_csr(
    const int* __restrict__ start, const int* __restrict__ srcs,
    const float* __restrict__ dinv, float* __restrict__ ew_s, int n) {
  int i = blockIdx.x * 256 + threadIdx.x;
  if (i >= n) return;
  int s = start[i], e = start[i + 1];
  float di = dinv[i];
  for (int p = s; p < e; ++p) ew_s[p] = dinv[srcs[p]] * ew_s[p] * di;
}

// out[i][:] = bias + snorm[i]*h[i][:] + sum_e wts[e]*h[srcs[e]][:]
// 32 lanes per node, float4 per lane (128 channels).
__global__ __launch_bounds__(256) void k_agg_csr(
    const float* __restrict__ h, const int* __restrict__ start,
    const int* __restrict__ srcs, const float* __restrict__ wts,
    const float* __restrict__ snorm, const float* __restrict__ bias,
    float* __restrict__ out, int n) {
  int tid = blockIdx.x * 256 + threadIdx.x;
  int i = tid >> 5;
  if (i >= n) return;
  int lane = tid & 31;
  const float4* h4 = (const float4*)h;
  float4 acc = ((const float4*)bias)[lane];
  float sn = snorm[i];
  float4 hv = h4[(size_t)i * 32 + lane];
  acc.x += sn * hv.x; acc.y += sn * hv.y;
  acc.z += sn * hv.z; acc.w += sn * hv.w;

  int e = start[i], eend = start[i + 1];
  for (; e + 4 <= eend; e += 4) {
    int r0 = srcs[e], r1 = srcs[e + 1], r2 = srcs[e + 2], r3 = srcs[e + 3];
    float w0 = wts[e], w1 = wts[e + 1], w2 = wts[e + 2], w3 = wts[e + 3];
    float4 v0 = h4[(size_t)r0 * 32 + lane];
    float4 v1 = h4[(size_t)r1 * 32 + lane];
    float4 v2 = h4[(size_t)r2 * 32 + lane];
    float4 v3 = h4[(size_t)r3 * 32 + lane];
    acc.x = fmaf(w0, v0.x, acc.x); acc.y = fmaf(w0, v0.y, acc.y);
    acc.z = fmaf(w0, v0.z, acc.z); acc.w = fmaf(w0, v0.w, acc.w);
    acc.x = fmaf(w1, v1.x, acc.x); acc.y = fmaf(w1, v1.y, acc.y);
    acc.z = fmaf(w1, v1.z, acc.z); acc.w = fmaf(w1, v1.w, acc.w);
    acc.x = fmaf(w2, v2.x, acc.x); acc.y = fmaf(w2, v2.y, acc.y);
    acc.z = fmaf(w2, v2.z, acc.z); acc.w = fmaf(w2, v2.w, acc.w);
    acc.x = fmaf(w3, v3.x, acc.x); acc.y = fmaf(w3, v3.y, acc.y);
    acc.z = fmaf(w3, v3.z, acc.z); acc.w = fmaf(w3, v3.w, acc.w);
  }
  for (; e < eend; ++e) {
    float w = wts[e];
    float4 v = h4[(size_t)srcs[e] * 32 + lane];
    acc.x = fmaf(w, v.x, acc.x); acc.y = fmaf(w, v.y, acc.y);
    acc.z = fmaf(w, v.z, acc.z); acc.w = fmaf(w, v.w, acc.w);
  }
  ((float4*)out)[(size_t)i * 32 + lane] = acc;
}

// GEMM: out[M x HOUT] = act( f(A[M x 128]) @ W[128 x HOUT] + bias )
// f = optional relu on input; ACT: 0 none, 1 relu, 2 sigmoid.
template <int HOUT, int ACT, bool RELU_IN>
__global__ __launch_bounds__(256) void k_gemm(
    const float* __restrict__ A, const float* __restrict__ W,
    const float* __restrict__ bias, float* __restrict__ out, int M) {
  constexpr int CG = HOUT / 4;     // thread column-groups (float4 wide)
  constexpr int TM = CG / 4;       // rows per thread
  __shared__ float Ws[128 * HOUT];
  __shared__ float Xs[64][132];

  const int t = threadIdx.x;
  const int m0 = blockIdx.x * 64;

  for (int i = t; i < 128 * HOUT / 4; i += 256)
    ((float4*)Ws)[i] = ((const float4*)W)[i];

  for (int i = t; i < 64 * 32; i += 256) {
    int r = i >> 5, c4 = i & 31;
    int gr = m0 + r;
    float4 v = make_float4(0.f, 0.f, 0.f, 0.f);
    if (gr < M) v = ((const float4*)A)[(size_t)gr * 32 + c4];
    if (RELU_IN) {
      v.x = fmaxf(v.x, 0.f); v.y = fmaxf(v.y, 0.f);
      v.z = fmaxf(v.z, 0.f); v.w = fmaxf(v.w, 0.f);
    }
    *(float4*)&Xs[r][c4 * 4] = v;
  }
  __syncthreads();

  const int tc = t % CG;
  const int tr = t / CG;
  float acc[TM][4];
#pragma unroll
  for (int i = 0; i < TM; ++i)
    acc[i][0] = acc[i][1] = acc[i][2] = acc[i][3] = 0.f;

#pragma unroll 4
  for (int k = 0; k < 128; ++k) {
    float4 wv = *(const float4*)&Ws[k * HOUT + tc * 4];
#pragma unroll
    for (int i = 0; i < TM; ++i) {
      float a = Xs[tr * TM + i][k];
      acc[i][0] = fmaf(a, wv.x, acc[i][0]);
      acc[i][1] = fmaf(a, wv.y, acc[i][1]);
      acc[i][2] = fmaf(a, wv.z, acc[i][2]);
      acc[i][3] = fmaf(a, wv.w, acc[i][3]);
    }
  }

#pragma unroll
  for (int i = 0; i < TM; ++i) {
    int gr = m0 + tr * TM + i;
    if (gr >= M) continue;
    float4 v = make_float4(acc[i][0], acc[i][1], acc[i][2], acc[i][3]);
    if (bias) {
      const float4 bv = *(const float4*)&bias[tc * 4];
      v.x += bv.x; v.y += bv.y; v.z += bv.z; v.w += bv.w;
    }
    if (ACT == 1) {
      v.x = fmaxf(v.x, 0.f); v.y = fmaxf(v.y, 0.f);
      v.z = fmaxf(v.z, 0.f); v.w = fmaxf(v.w, 0.f);
    } else if (ACT == 2) {
      v.x = 1.f / (1.f + __expf(-v.x));
      v.y = 1.f / (1.f + __expf(-v.y));
      v.z = 1.f / (1.f + __expf(-v.z));
      v.w = 1.f / (1.f + __expf(-v.w));
    }
    ((float4*)out)[(size_t)gr * CG + tc] = v;
  }
}

extern "C" void kernel_launch(void* const* d_in, const int* in_sizes, int n_in,
                              void* d_out, int out_size, void* d_ws, size_t ws_size,
                              hipStream_t stream) {
  const float* x        = (const float*)d_in[0];
  const float* edge_emb = (const float*)d_in[1];
  const float* W1 = (const float*)d_in[2];  const float* b1 = (const float*)d_in[3];
  const float* W2 = (const float*)d_in[4];  const float* b2 = (const float*)d_in[5];
  const float* W3 = (const float*)d_in[6];  const float* b3 = (const float*)d_in[7];
  const float* cW1 = (const float*)d_in[8]; const float* cb1 = (const float*)d_in[9];
  const float* cW2 = (const float*)d_in[10]; const float* cb2 = (const float*)d_in[11];
  const int* eidx  = (const int*)d_in[12];
  const int* eattr = (const int*)d_in[13];

  const int N = in_sizes[0] / 128;
  const int E = in_sizes[13];
  const int* row = eidx;        // edge_index[0] = source
  const int* col = eidx + E;    // edge_index[1] = target

  float* out = (float*)d_out;

  // workspace layout, 16B-aligned slots (element counts rounded to x4)
  size_t off = 0;
  auto alloc4 = [&](size_t n) { size_t o = off; off += (n + 3) & ~(size_t)3; return o; };
  float* wsf = (float*)d_ws;
  int*   wsi = (int*)d_ws;

  float* dinv   = wsf + alloc4(N);
  float* snorm  = wsf + alloc4(N);
  int*   cnt    = wsi + alloc4(N);
  int*   start  = wsi + alloc4(N + 1);
  int*   bsum   = wsi + alloc4(256);
  int*   rank   = wsi + alloc4(E);
  int*   srcs   = wsi + alloc4(E);
  float* wts    = wsf + alloc4(E);   // filled with raw ew, normalized in place
  float* bufA   = wsf + alloc4((size_t)N * 128);
  float* bufB   = wsf + alloc4((size_t)N * 128);

  const int gN  = (N + 255) / 256;
  const int gE  = (E + 255) / 256;
  const int gG  = (N + 63) / 64;
  const int gA  = (N * 32 + 255) / 256;
  const int nb  = gN;  // scan blocks

  // ---- graph preprocessing (once, reused by all 3 layers) ----
  k_init<<<gN, 256, 0, stream>>>(cnt, N);
  k_hist<<<gE, 256, 0, stream>>>(col, cnt, rank, E);
  k_scan1<<<nb, 256, 0, stream>>>(cnt, start, bsum, N);
  k_scan2<<<1, 256, 0, stream>>>(bsum, nb);
  k_scan3<<<nb, 256, 0, stream>>>(start, bsum, N);
  k_fill<<<gE, 256, 0, stream>>>(eattr, edge_emb, row, col, rank, start,
                                 srcs, wts, E);
  k_deg_csr<<<gN, 256, 0, stream>>>(start, wts, dinv, snorm, N);
  k_wts_csr<<<gN, 256, 0, stream>>>(start, srcs, dinv, wts, N);

  // ---- layer 1 ----
  k_gemm<128, 0, false><<<gG, 256, 0, stream>>>(x, W1, nullptr, bufA, N);
  k_agg_csr<<<gA, 256, 0, stream>>>(bufA, start, srcs, wts, snorm, b1, bufB, N);
  // ---- layer 2 (relu fused into GEMM input load) ----
  k_gemm<128, 0, true><<<gG, 256, 0, stream>>>(bufB, W2, nullptr, bufA, N);
  k_agg_csr<<<gA, 256, 0, stream>>>(bufA, start, srcs, wts, snorm, b2, bufB, N);
  // ---- layer 3 ----
  k_gemm<128, 0, true><<<gG, 256, 0, stream>>>(bufB, W3, nullptr, bufA, N);
  k_agg_csr<<<gA, 256, 0, stream>>>(bufA, start, srcs, wts, snorm, b3, bufB, N);

  // ---- classifier ----
  k_gemm<128, 1, true><<<gG, 256, 0, stream>>>(bufB, cW1, cb1, bufA, N);
  k_gemm<64, 2, false><<<gG, 256, 0, stream>>>(bufA, cW2, cb2, out, N);
}

// Round 4
// 452.602 us; speedup vs baseline: 3.0143x; 1.2090x over previous
//
#include <hip/hip_runtime.h>
#include <cstdint>
#include <cstddef>

// ---------------------------------------------------------------------------
// CADGroupingGNN: 3x GCNConv(128->128) + MLP classifier, N=50000, E=800000.
// Round 3: GEMM occupancy fix. BN=64 col-tiles (Ws 32KB) + Xs 33KB = 66KB LDS
// -> 2 blocks/CU (was 99KB -> 1 block/CU). Persistent blocks stage W once and
// stride over row tiles. float4 LDS reads (8 x ds_read_b128 per 64 FMA).
// ---------------------------------------------------------------------------

__global__ __launch_bounds__(256) void k_init(int* __restrict__ cnt, int n) {
  int i = blockIdx.x * 256 + threadIdx.x;
  if (i < n) cnt[i] = 0;
}

// in-degree histogram; returned old count = edge's slot within its bucket
__global__ __launch_bounds__(256) void k_hist(
    const int* __restrict__ col, int* __restrict__ cnt,
    int* __restrict__ rank, int E) {
  int e = blockIdx.x * 256 + threadIdx.x;
  if (e < E) rank[e] = atomicAdd(&cnt[col[e]], 1);
}

// ---- exclusive scan of cnt[] over N elements (3 kernels) ----
__global__ __launch_bounds__(256) void k_scan1(
    const int* __restrict__ cnt, int* __restrict__ start,
    int* __restrict__ bsum, int n) {
  __shared__ int s[256];
  int t = threadIdx.x, idx = blockIdx.x * 256 + t;
  s[t] = (idx < n) ? cnt[idx] : 0;
  for (int d = 1; d < 256; d <<= 1) {
    __syncthreads();
    int x = (t >= d) ? s[t - d] : 0;
    __syncthreads();
    s[t] += x;
  }
  __syncthreads();
  if (idx < n) start[idx + 1] = s[t];          // inclusive, per-block
  if (t == 255) bsum[blockIdx.x] = s[255];
}

__global__ __launch_bounds__(256) void k_scan2(int* __restrict__ bsum, int nb) {
  __shared__ int s[256];
  int t = threadIdx.x;
  s[t] = (t < nb) ? bsum[t] : 0;
  for (int d = 1; d < 256; d <<= 1) {
    __syncthreads();
    int x = (t >= d) ? s[t - d] : 0;
    __syncthreads();
    s[t] += x;
  }
  __syncthreads();
  if (t < nb) bsum[t] = s[t];                  // inclusive block sums
}

__global__ __launch_bounds__(256) void k_scan3(
    int* __restrict__ start, const int* __restrict__ bsum, int n) {
  int b = blockIdx.x, idx = b * 256 + threadIdx.x;
  if (idx < n) {
    int off = (b > 0) ? bsum[b - 1] : 0;
    start[idx + 1] += off;
    if (idx == 0) start[0] = 0;
  }
}

// atomic-free bucket fill: p = start[col] + rank
__global__ __launch_bounds__(256) void k_fill(
    const int* __restrict__ attr, const float* __restrict__ emb,
    const int* __restrict__ row, const int* __restrict__ col,
    const int* __restrict__ rank, const int* __restrict__ start,
    int* __restrict__ srcs, float* __restrict__ ew_s, int E) {
  int e = blockIdx.x * 256 + threadIdx.x;
  if (e < E) {
    int p = start[col[e]] + rank[e];
    srcs[p] = row[e];
    ew_s[p] = emb[attr[e]];
  }
}

// per-node deterministic degree sum -> dinv, snorm
__global__ __launch_bounds__(256) void k_deg_csr(
    const int* __restrict__ start, const float* __restrict__ ew_s,
    float* __restrict__ dinv, float* __restrict__ snorm, int n) {
  int i = blockIdx.x * 256 + threadIdx.x;
  if (i >= n) return;
  int s = start[i], e = start[i + 1];
  float d = 1.0f;                              // self-loop weight
  for (int p = s; p < e; ++p) d += ew_s[p];
  float v = d > 0.f ? rsqrtf(d) : 0.f;
  dinv[i] = v;
  snorm[i] = v * v;
}

// per-node in-place weight normalization: ew_s[p] *= dinv[src]*dinv[i]
__global__ __launch_bounds__(256) void k_wts_csr(
    const int* __restrict__ start, const int* __restrict__ srcs,
    const float* __restrict__ dinv, float* __restrict__ ew_s, int n) {
  int i = blockIdx.x * 256 + threadIdx.x;
  if (i >= n) return;
  int s = start[i], e = start[i + 1];
  float di = dinv[i];
  for (int p = s; p < e; ++p) ew_s[p] = dinv[srcs[p]] * ew_s[p] * di;
}

// out[i][:] = bias + snorm[i]*h[i][:] + sum_e wts[e]*h[srcs[e]][:]
// 32 lanes per node, float4 per lane (128 channels).
__global__ __launch_bounds__(256) void k_agg_csr(
    const float* __restrict__ h, const int* __restrict__ start,
    const int* __restrict__ srcs, const float* __restrict__ wts,
    const float* __restrict__ snorm, const float* __restrict__ bias,
    float* __restrict__ out, int n) {
  int tid = blockIdx.x * 256 + threadIdx.x;
  int i = tid >> 5;
  if (i >= n) return;
  int lane = tid & 31;
  const float4* h4 = (const float4*)h;
  float4 acc = ((const float4*)bias)[lane];
  float sn = snorm[i];
  float4 hv = h4[(size_t)i * 32 + lane];
  acc.x += sn * hv.x; acc.y += sn * hv.y;
  acc.z += sn * hv.z; acc.w += sn * hv.w;

  int e = start[i], eend = start[i + 1];
  for (; e + 4 <= eend; e += 4) {
    int r0 = srcs[e], r1 = srcs[e + 1], r2 = srcs[e + 2], r3 = srcs[e + 3];
    float w0 = wts[e], w1 = wts[e + 1], w2 = wts[e + 2], w3 = wts[e + 3];
    float4 v0 = h4[(size_t)r0 * 32 + lane];
    float4 v1 = h4[(size_t)r1 * 32 + lane];
    float4 v2 = h4[(size_t)r2 * 32 + lane];
    float4 v3 = h4[(size_t)r3 * 32 + lane];
    acc.x = fmaf(w0, v0.x, acc.x); acc.y = fmaf(w0, v0.y, acc.y);
    acc.z = fmaf(w0, v0.z, acc.z); acc.w = fmaf(w0, v0.w, acc.w);
    acc.x = fmaf(w1, v1.x, acc.x); acc.y = fmaf(w1, v1.y, acc.y);
    acc.z = fmaf(w1, v1.z, acc.z); acc.w = fmaf(w1, v1.w, acc.w);
    acc.x = fmaf(w2, v2.x, acc.x); acc.y = fmaf(w2, v2.y, acc.y);
    acc.z = fmaf(w2, v2.z, acc.z); acc.w = fmaf(w2, v2.w, acc.w);
    acc.x = fmaf(w3, v3.x, acc.x); acc.y = fmaf(w3, v3.y, acc.y);
    acc.z = fmaf(w3, v3.z, acc.z); acc.w = fmaf(w3, v3.w, acc.w);
  }
  for (; e < eend; ++e) {
    float w = wts[e];
    float4 v = h4[(size_t)srcs[e] * 32 + lane];
    acc.x = fmaf(w, v.x, acc.x); acc.y = fmaf(w, v.y, acc.y);
    acc.z = fmaf(w, v.z, acc.z); acc.w = fmaf(w, v.w, acc.w);
  }
  ((float4*)out)[(size_t)i * 32 + lane] = acc;
}

// GEMM: out[M x HOUT] = act( f(A[M x 128]) @ W[128 x HOUT] + bias )
// BN=64 col tiles; persistent blocks (W staged once); 2 blocks/CU.
// ACT: 0 none, 1 relu, 2 sigmoid. RELU_IN: relu applied to A on load.
template <int HOUT, int ACT, bool RELU_IN>
__global__ __launch_bounds__(256, 2) void k_gemm(
    const float* __restrict__ A, const float* __restrict__ W,
    const float* __restrict__ bias, float* __restrict__ out, int M) {
  constexpr int NCT = HOUT / 64;   // column tiles
  constexpr int W4R = HOUT / 4;    // float4 per W row
  __shared__ float Ws[128 * 64];   // 32 KB: this block's 64-col slice of W
  __shared__ float Xs[64][132];    // 33 KB

  const int t = threadIdx.x;
  const int ct = blockIdx.x % NCT;
  const int rt0 = blockIdx.x / NCT;
  const int rstride = gridDim.x / NCT;
  const int ntiles = (M + 63) >> 6;

  // stage Ws: 2048 float4
  for (int i = t; i < 128 * 16; i += 256) {
    int k = i >> 4, j4 = i & 15;
    ((float4*)Ws)[i] = ((const float4*)W)[k * W4R + ct * 16 + j4];
  }

  const int tc = t & 15;           // 16 column groups (4 cols each)
  const int tr = t >> 4;           // 16 row groups (4 rows each)
  const float4* A4 = (const float4*)A;

  for (int rt = rt0; rt < ntiles; rt += rstride) {
    __syncthreads();               // prev compute done (and Ws staged, 1st iter)
    const int m0 = rt << 6;
    for (int i = t; i < 64 * 32; i += 256) {
      int r = i >> 5, c4 = i & 31;
      int gr = m0 + r;
      float4 v = make_float4(0.f, 0.f, 0.f, 0.f);
      if (gr < M) v = A4[(size_t)gr * 32 + c4];
      if (RELU_IN) {
        v.x = fmaxf(v.x, 0.f); v.y = fmaxf(v.y, 0.f);
        v.z = fmaxf(v.z, 0.f); v.w = fmaxf(v.w, 0.f);
      }
      *(float4*)&Xs[r][c4 * 4] = v;
    }
    __syncthreads();

    float acc[4][4];
#pragma unroll
    for (int rr = 0; rr < 4; ++rr)
      acc[rr][0] = acc[rr][1] = acc[rr][2] = acc[rr][3] = 0.f;

#pragma unroll 4
    for (int k4 = 0; k4 < 32; ++k4) {
      float4 wv[4], av[4];
#pragma unroll
      for (int kk = 0; kk < 4; ++kk)
        wv[kk] = ((const float4*)Ws)[(k4 * 4 + kk) * 16 + tc];
#pragma unroll
      for (int rr = 0; rr < 4; ++rr)
        av[rr] = *(const float4*)&Xs[tr * 4 + rr][k4 * 4];
#pragma unroll
      for (int rr = 0; rr < 4; ++rr) {
        acc[rr][0] = fmaf(av[rr].x, wv[0].x, acc[rr][0]);
        acc[rr][1] = fmaf(av[rr].x, wv[0].y, acc[rr][1]);
        acc[rr][2] = fmaf(av[rr].x, wv[0].z, acc[rr][2]);
        acc[rr][3] = fmaf(av[rr].x, wv[0].w, acc[rr][3]);
        acc[rr][0] = fmaf(av[rr].y, wv[1].x, acc[rr][0]);
        acc[rr][1] = fmaf(av[rr].y, wv[1].y, acc[rr][1]);
        acc[rr][2] = fmaf(av[rr].y, wv[1].z, acc[rr][2]);
        acc[rr][3] = fmaf(av[rr].y, wv[1].w, acc[rr][3]);
        acc[rr][0] = fmaf(av[rr].z, wv[2].x, acc[rr][0]);
        acc[rr][1] = fmaf(av[rr].z, wv[2].y, acc[rr][1]);
        acc[rr][2] = fmaf(av[rr].z, wv[2].z, acc[rr][2]);
        acc[rr][3] = fmaf(av[rr].z, wv[2].w, acc[rr][3]);
        acc[rr][0] = fmaf(av[rr].w, wv[3].x, acc[rr][0]);
        acc[rr][1] = fmaf(av[rr].w, wv[3].y, acc[rr][1]);
        acc[rr][2] = fmaf(av[rr].w, wv[3].z, acc[rr][2]);
        acc[rr][3] = fmaf(av[rr].w, wv[3].w, acc[rr][3]);
      }
    }

#pragma unroll
    for (int rr = 0; rr < 4; ++rr) {
      int gr = m0 + tr * 4 + rr;
      if (gr >= M) continue;
      float4 v = make_float4(acc[rr][0], acc[rr][1], acc[rr][2], acc[rr][3]);
      if (bias) {
        const float4 bv = *(const float4*)&bias[ct * 64 + tc * 4];
        v.x += bv.x; v.y += bv.y; v.z += bv.z; v.w += bv.w;
      }
      if (ACT == 1) {
        v.x = fmaxf(v.x, 0.f); v.y = fmaxf(v.y, 0.f);
        v.z = fmaxf(v.z, 0.f); v.w = fmaxf(v.w, 0.f);
      } else if (ACT == 2) {
        v.x = 1.f / (1.f + __expf(-v.x));
        v.y = 1.f / (1.f + __expf(-v.y));
        v.z = 1.f / (1.f + __expf(-v.z));
        v.w = 1.f / (1.f + __expf(-v.w));
      }
      ((float4*)out)[(size_t)gr * W4R + ct * 16 + tc] = v;
    }
  }
}

extern "C" void kernel_launch(void* const* d_in, const int* in_sizes, int n_in,
                              void* d_out, int out_size, void* d_ws, size_t ws_size,
                              hipStream_t stream) {
  const float* x        = (const float*)d_in[0];
  const float* edge_emb = (const float*)d_in[1];
  const float* W1 = (const float*)d_in[2];  const float* b1 = (const float*)d_in[3];
  const float* W2 = (const float*)d_in[4];  const float* b2 = (const float*)d_in[5];
  const float* W3 = (const float*)d_in[6];  const float* b3 = (const float*)d_in[7];
  const float* cW1 = (const float*)d_in[8]; const float* cb1 = (const float*)d_in[9];
  const float* cW2 = (const float*)d_in[10]; const float* cb2 = (const float*)d_in[11];
  const int* eidx  = (const int*)d_in[12];
  const int* eattr = (const int*)d_in[13];

  const int N = in_sizes[0] / 128;
  const int E = in_sizes[13];
  const int* row = eidx;        // edge_index[0] = source
  const int* col = eidx + E;    // edge_index[1] = target

  float* out = (float*)d_out;

  // workspace layout, 16B-aligned slots (element counts rounded to x4)
  size_t off = 0;
  auto alloc4 = [&](size_t n) { size_t o = off; off += (n + 3) & ~(size_t)3; return o; };
  float* wsf = (float*)d_ws;
  int*   wsi = (int*)d_ws;

  float* dinv   = wsf + alloc4(N);
  float* snorm  = wsf + alloc4(N);
  int*   cnt    = wsi + alloc4(N);
  int*   start  = wsi + alloc4(N + 1);
  int*   bsum   = wsi + alloc4(256);
  int*   rank   = wsi + alloc4(E);
  int*   srcs   = wsi + alloc4(E);
  float* wts    = wsf + alloc4(E);   // raw ew, normalized in place
  float* bufA   = wsf + alloc4((size_t)N * 128);
  float* bufB   = wsf + alloc4((size_t)N * 128);

  const int gN  = (N + 255) / 256;
  const int gE  = (E + 255) / 256;
  const int gA  = (N * 32 + 255) / 256;
  const int nb  = gN;  // scan blocks
  const int gGemm = 512;   // persistent: 2 blocks/CU

  // ---- graph preprocessing (once, reused by all 3 layers) ----
  k_init<<<gN, 256, 0, stream>>>(cnt, N);
  k_hist<<<gE, 256, 0, stream>>>(col, cnt, rank, E);
  k_scan1<<<nb, 256, 0, stream>>>(cnt, start, bsum, N);
  k_scan2<<<1, 256, 0, stream>>>(bsum, nb);
  k_scan3<<<nb, 256, 0, stream>>>(start, bsum, N);
  k_fill<<<gE, 256, 0, stream>>>(eattr, edge_emb, row, col, rank, start,
                                 srcs, wts, E);
  k_deg_csr<<<gN, 256, 0, stream>>>(start, wts, dinv, snorm, N);
  k_wts_csr<<<gN, 256, 0, stream>>>(start, srcs, dinv, wts, N);

  // ---- layer 1 ----
  k_gemm<128, 0, false><<<gGemm, 256, 0, stream>>>(x, W1, nullptr, bufA, N);
  k_agg_csr<<<gA, 256, 0, stream>>>(bufA, start, srcs, wts, snorm, b1, bufB, N);
  // ---- layer 2 (relu fused into GEMM input load) ----
  k_gemm<128, 0, true><<<gGemm, 256, 0, stream>>>(bufB, W2, nullptr, bufA, N);
  k_agg_csr<<<gA, 256, 0, stream>>>(bufA, start, srcs, wts, snorm, b2, bufB, N);
  // ---- layer 3 ----
  k_gemm<128, 0, true><<<gGemm, 256, 0, stream>>>(bufB, W3, nullptr, bufA, N);
  k_agg_csr<<<gA, 256, 0, stream>>>(bufA, start, srcs, wts, snorm, b3, bufB, N);

  // ---- classifier ----
  k_gemm<128, 1, true><<<gGemm, 256, 0, stream>>>(bufB, cW1, cb1, bufA, N);
  k_gemm<64, 2, false><<<gGemm, 256, 0, stream>>>(bufA, cW2, cb2, out, N);
}

// Round 6
// 448.302 us; speedup vs baseline: 3.0432x; 1.0096x over previous
//
#include <hip/hip_runtime.h>
#include <cstdint>
#include <cstddef>

// ---------------------------------------------------------------------------
// CADGroupingGNN: 3x GCNConv(128->128) + MLP classifier, N=50000, E=800000.
// Round 5: round-4 retry (macro token-collision fix: AGG_FMA param `w`
// clobbered `.w` member accesses; now an inline function).
// k_agg_csr: 8-deep gather unroll, broadcast int4/float4 index loads,
// 8 independent 512B gathers in flight per 32-lane node group.
// ---------------------------------------------------------------------------

__global__ __launch_bounds__(256) void k_init(int* __restrict__ cnt, int n) {
  int i = blockIdx.x * 256 + threadIdx.x;
  if (i < n) cnt[i] = 0;
}

// in-degree histogram; returned old count = edge's slot within its bucket
__global__ __launch_bounds__(256) void k_hist(
    const int* __restrict__ col, int* __restrict__ cnt,
    int* __restrict__ rank, int E) {
  int e = blockIdx.x * 256 + threadIdx.x;
  if (e < E) rank[e] = atomicAdd(&cnt[col[e]], 1);
}

// ---- exclusive scan of cnt[] over N elements (3 kernels) ----
__global__ __launch_bounds__(256) void k_scan1(
    const int* __restrict__ cnt, int* __restrict__ start,
    int* __restrict__ bsum, int n) {
  __shared__ int s[256];
  int t = threadIdx.x, idx = blockIdx.x * 256 + t;
  s[t] = (idx < n) ? cnt[idx] : 0;
  for (int d = 1; d < 256; d <<= 1) {
    __syncthreads();
    int x = (t >= d) ? s[t - d] : 0;
    __syncthreads();
    s[t] += x;
  }
  __syncthreads();
  if (idx < n) start[idx + 1] = s[t];          // inclusive, per-block
  if (t == 255) bsum[blockIdx.x] = s[255];
}

__global__ __launch_bounds__(256) void k_scan2(int* __restrict__ bsum, int nb) {
  __shared__ int s[256];
  int t = threadIdx.x;
  s[t] = (t < nb) ? bsum[t] : 0;
  for (int d = 1; d < 256; d <<= 1) {
    __syncthreads();
    int x = (t >= d) ? s[t - d] : 0;
    __syncthreads();
    s[t] += x;
  }
  __syncthreads();
  if (t < nb) bsum[t] = s[t];                  // inclusive block sums
}

__global__ __launch_bounds__(256) void k_scan3(
    int* __restrict__ start, const int* __restrict__ bsum, int n) {
  int b = blockIdx.x, idx = b * 256 + threadIdx.x;
  if (idx < n) {
    int off = (b > 0) ? bsum[b - 1] : 0;
    start[idx + 1] += off;
    if (idx == 0) start[0] = 0;
  }
}

// atomic-free bucket fill: p = start[col] + rank
__global__ __launch_bounds__(256) void k_fill(
    const int* __restrict__ attr, const float* __restrict__ emb,
    const int* __restrict__ row, const int* __restrict__ col,
    const int* __restrict__ rank, const int* __restrict__ start,
    int* __restrict__ srcs, float* __restrict__ ew_s, int E) {
  int e = blockIdx.x * 256 + threadIdx.x;
  if (e < E) {
    int p = start[col[e]] + rank[e];
    srcs[p] = row[e];
    ew_s[p] = emb[attr[e]];
  }
}

// per-node deterministic degree sum -> dinv, snorm
__global__ __launch_bounds__(256) void k_deg_csr(
    const int* __restrict__ start, const float* __restrict__ ew_s,
    float* __restrict__ dinv, float* __restrict__ snorm, int n) {
  int i = blockIdx.x * 256 + threadIdx.x;
  if (i >= n) return;
  int s = start[i], e = start[i + 1];
  float d = 1.0f;                              // self-loop weight
  for (int p = s; p < e; ++p) d += ew_s[p];
  float v = d > 0.f ? rsqrtf(d) : 0.f;
  dinv[i] = v;
  snorm[i] = v * v;
}

// per-node in-place weight normalization: ew_s[p] *= dinv[src]*dinv[i]
__global__ __launch_bounds__(256) void k_wts_csr(
    const int* __restrict__ start, const int* __restrict__ srcs,
    const float* __restrict__ dinv, float* __restrict__ ew_s, int n) {
  int i = blockIdx.x * 256 + threadIdx.x;
  if (i >= n) return;
  int s = start[i], e = start[i + 1];
  float di = dinv[i];
  for (int p = s; p < e; ++p) ew_s[p] = dinv[srcs[p]] * ew_s[p] * di;
}

__device__ __forceinline__ void agg_fma(float s, const float4& v, float4& acc) {
  acc.x = fmaf(s, v.x, acc.x);
  acc.y = fmaf(s, v.y, acc.y);
  acc.z = fmaf(s, v.z, acc.z);
  acc.w = fmaf(s, v.w, acc.w);
}

// out[i][:] = bias + snorm[i]*h[i][:] + sum_e wts[e]*h[srcs[e]][:]
// 32 lanes per node, float4 per lane (128 channels). 8-deep gather pipeline.
__global__ __launch_bounds__(256) void k_agg_csr(
    const float* __restrict__ h, const int* __restrict__ start,
    const int* __restrict__ srcs, const float* __restrict__ wts,
    const float* __restrict__ snorm, const float* __restrict__ bias,
    float* __restrict__ out, int n) {
  int tid = blockIdx.x * 256 + threadIdx.x;
  int i = tid >> 5;
  if (i >= n) return;
  int lane = tid & 31;
  const float4* h4 = (const float4*)h;
  float4 acc = ((const float4*)bias)[lane];
  float sn = snorm[i];
  float4 hv = h4[(size_t)i * 32 + lane];
  acc.x += sn * hv.x; acc.y += sn * hv.y;
  acc.z += sn * hv.z; acc.w += sn * hv.w;

  int e = start[i], eend = start[i + 1];

  // head: advance to 4-edge alignment so int4/float4 loads are 16B-aligned
  while (e < eend && (e & 3)) {
    float w = wts[e];
    float4 v = h4[(size_t)srcs[e] * 32 + lane];
    agg_fma(w, v, acc);
    ++e;
  }

  // body: 8 edges per iteration, 2 broadcast index loads, 8 gathers in flight
  for (; e + 8 <= eend; e += 8) {
    int4   s0 = *(const int4*)&srcs[e];
    int4   s1 = *(const int4*)&srcs[e + 4];
    float4 w0 = *(const float4*)&wts[e];
    float4 w1 = *(const float4*)&wts[e + 4];
    float4 v0 = h4[(size_t)s0.x * 32 + lane];
    float4 v1 = h4[(size_t)s0.y * 32 + lane];
    float4 v2 = h4[(size_t)s0.z * 32 + lane];
    float4 v3 = h4[(size_t)s0.w * 32 + lane];
    float4 v4 = h4[(size_t)s1.x * 32 + lane];
    float4 v5 = h4[(size_t)s1.y * 32 + lane];
    float4 v6 = h4[(size_t)s1.z * 32 + lane];
    float4 v7 = h4[(size_t)s1.w * 32 + lane];
    agg_fma(w0.x, v0, acc); agg_fma(w0.y, v1, acc);
    agg_fma(w0.z, v2, acc); agg_fma(w0.w, v3, acc);
    agg_fma(w1.x, v4, acc); agg_fma(w1.y, v5, acc);
    agg_fma(w1.z, v6, acc); agg_fma(w1.w, v7, acc);
  }

  // 4-edge step
  if (e + 4 <= eend) {
    int4   s0 = *(const int4*)&srcs[e];
    float4 w0 = *(const float4*)&wts[e];
    float4 v0 = h4[(size_t)s0.x * 32 + lane];
    float4 v1 = h4[(size_t)s0.y * 32 + lane];
    float4 v2 = h4[(size_t)s0.z * 32 + lane];
    float4 v3 = h4[(size_t)s0.w * 32 + lane];
    agg_fma(w0.x, v0, acc); agg_fma(w0.y, v1, acc);
    agg_fma(w0.z, v2, acc); agg_fma(w0.w, v3, acc);
    e += 4;
  }

  // tail
  for (; e < eend; ++e) {
    float w = wts[e];
    float4 v = h4[(size_t)srcs[e] * 32 + lane];
    agg_fma(w, v, acc);
  }

  ((float4*)out)[(size_t)i * 32 + lane] = acc;
}

// GEMM: out[M x HOUT] = act( f(A[M x 128]) @ W[128 x HOUT] + bias )
// BN=64 col tiles; persistent blocks (W staged once); 2 blocks/CU.
// ACT: 0 none, 1 relu, 2 sigmoid. RELU_IN: relu applied to A on load.
template <int HOUT, int ACT, bool RELU_IN>
__global__ __launch_bounds__(256, 2) void k_gemm(
    const float* __restrict__ A, const float* __restrict__ W,
    const float* __restrict__ bias, float* __restrict__ out, int M) {
  constexpr int NCT = HOUT / 64;   // column tiles
  constexpr int W4R = HOUT / 4;    // float4 per W row
  __shared__ float Ws[128 * 64];   // 32 KB: this block's 64-col slice of W
  __shared__ float Xs[64][132];    // 33 KB

  const int t = threadIdx.x;
  const int ct = blockIdx.x % NCT;
  const int rt0 = blockIdx.x / NCT;
  const int rstride = gridDim.x / NCT;
  const int ntiles = (M + 63) >> 6;

  // stage Ws: 2048 float4
  for (int i = t; i < 128 * 16; i += 256) {
    int k = i >> 4, j4 = i & 15;
    ((float4*)Ws)[i] = ((const float4*)W)[k * W4R + ct * 16 + j4];
  }

  const int tc = t & 15;           // 16 column groups (4 cols each)
  const int tr = t >> 4;           // 16 row groups (4 rows each)
  const float4* A4 = (const float4*)A;

  for (int rt = rt0; rt < ntiles; rt += rstride) {
    __syncthreads();               // prev compute done (and Ws staged, 1st iter)
    const int m0 = rt << 6;
    for (int i = t; i < 64 * 32; i += 256) {
      int r = i >> 5, c4 = i & 31;
      int gr = m0 + r;
      float4 v = make_float4(0.f, 0.f, 0.f, 0.f);
      if (gr < M) v = A4[(size_t)gr * 32 + c4];
      if (RELU_IN) {
        v.x = fmaxf(v.x, 0.f); v.y = fmaxf(v.y, 0.f);
        v.z = fmaxf(v.z, 0.f); v.w = fmaxf(v.w, 0.f);
      }
      *(float4*)&Xs[r][c4 * 4] = v;
    }
    __syncthreads();

    float acc[4][4];
#pragma unroll
    for (int rr = 0; rr < 4; ++rr)
      acc[rr][0] = acc[rr][1] = acc[rr][2] = acc[rr][3] = 0.f;

#pragma unroll 4
    for (int k4 = 0; k4 < 32; ++k4) {
      float4 wv[4], av[4];
#pragma unroll
      for (int kk = 0; kk < 4; ++kk)
        wv[kk] = ((const float4*)Ws)[(k4 * 4 + kk) * 16 + tc];
#pragma unroll
      for (int rr = 0; rr < 4; ++rr)
        av[rr] = *(const float4*)&Xs[tr * 4 + rr][k4 * 4];
#pragma unroll
      for (int rr = 0; rr < 4; ++rr) {
        acc[rr][0] = fmaf(av[rr].x, wv[0].x, acc[rr][0]);
        acc[rr][1] = fmaf(av[rr].x, wv[0].y, acc[rr][1]);
        acc[rr][2] = fmaf(av[rr].x, wv[0].z, acc[rr][2]);
        acc[rr][3] = fmaf(av[rr].x, wv[0].w, acc[rr][3]);
        acc[rr][0] = fmaf(av[rr].y, wv[1].x, acc[rr][0]);
        acc[rr][1] = fmaf(av[rr].y, wv[1].y, acc[rr][1]);
        acc[rr][2] = fmaf(av[rr].y, wv[1].z, acc[rr][2]);
        acc[rr][3] = fmaf(av[rr].y, wv[1].w, acc[rr][3]);
        acc[rr][0] = fmaf(av[rr].z, wv[2].x, acc[rr][0]);
        acc[rr][1] = fmaf(av[rr].z, wv[2].y, acc[rr][1]);
        acc[rr][2] = fmaf(av[rr].z, wv[2].z, acc[rr][2]);
        acc[rr][3] = fmaf(av[rr].z, wv[2].w, acc[rr][3]);
        acc[rr][0] = fmaf(av[rr].w, wv[3].x, acc[rr][0]);
        acc[rr][1] = fmaf(av[rr].w, wv[3].y, acc[rr][1]);
        acc[rr][2] = fmaf(av[rr].w, wv[3].z, acc[rr][2]);
        acc[rr][3] = fmaf(av[rr].w, wv[3].w, acc[rr][3]);
      }
    }

#pragma unroll
    for (int rr = 0; rr < 4; ++rr) {
      int gr = m0 + tr * 4 + rr;
      if (gr >= M) continue;
      float4 v = make_float4(acc[rr][0], acc[rr][1], acc[rr][2], acc[rr][3]);
      if (bias) {
        const float4 bv = *(const float4*)&bias[ct * 64 + tc * 4];
        v.x += bv.x; v.y += bv.y; v.z += bv.z; v.w += bv.w;
      }
      if (ACT == 1) {
        v.x = fmaxf(v.x, 0.f); v.y = fmaxf(v.y, 0.f);
        v.z = fmaxf(v.z, 0.f); v.w = fmaxf(v.w, 0.f);
      } else if (ACT == 2) {
        v.x = 1.f / (1.f + __expf(-v.x));
        v.y = 1.f / (1.f + __expf(-v.y));
        v.z = 1.f / (1.f + __expf(-v.z));
        v.w = 1.f / (1.f + __expf(-v.w));
      }
      ((float4*)out)[(size_t)gr * W4R + ct * 16 + tc] = v;
    }
  }
}

extern "C" void kernel_launch(void* const* d_in, const int* in_sizes, int n_in,
                              void* d_out, int out_size, void* d_ws, size_t ws_size,
                              hipStream_t stream) {
  const float* x        = (const float*)d_in[0];
  const float* edge_emb = (const float*)d_in[1];
  const float* W1 = (const float*)d_in[2];  const float* b1 = (const float*)d_in[3];
  const float* W2 = (const float*)d_in[4];  const float* b2 = (const float*)d_in[5];
  const float* W3 = (const float*)d_in[6];  const float* b3 = (const float*)d_in[7];
  const float* cW1 = (const float*)d_in[8]; const float* cb1 = (const float*)d_in[9];
  const float* cW2 = (const float*)d_in[10]; const float* cb2 = (const float*)d_in[11];
  const int* eidx  = (const int*)d_in[12];
  const int* eattr = (const int*)d_in[13];

  const int N = in_sizes[0] / 128;
  const int E = in_sizes[13];
  const int* row = eidx;        // edge_index[0] = source
  const int* col = eidx + E;    // edge_index[1] = target

  float* out = (float*)d_out;

  // workspace layout, 16B-aligned slots (element counts rounded to x4)
  size_t off = 0;
  auto alloc4 = [&](size_t n) { size_t o = off; off += (n + 3) & ~(size_t)3; return o; };
  float* wsf = (float*)d_ws;
  int*   wsi = (int*)d_ws;

  float* dinv   = wsf + alloc4(N);
  float* snorm  = wsf + alloc4(N);
  int*   cnt    = wsi + alloc4(N);
  int*   start  = wsi + alloc4(N + 1);
  int*   bsum   = wsi + alloc4(256);
  int*   rank   = wsi + alloc4(E);
  int*   srcs   = wsi + alloc4(E);
  float* wts    = wsf + alloc4(E);   // raw ew, normalized in place
  float* bufA   = wsf + alloc4((size_t)N * 128);
  float* bufB   = wsf + alloc4((size_t)N * 128);

  const int gN  = (N + 255) / 256;
  const int gE  = (E + 255) / 256;
  const int gA  = (N * 32 + 255) / 256;
  const int nb  = gN;  // scan blocks
  const int gGemm = 512;   // persistent: 2 blocks/CU

  // ---- graph preprocessing (once, reused by all 3 layers) ----
  k_init<<<gN, 256, 0, stream>>>(cnt, N);
  k_hist<<<gE, 256, 0, stream>>>(col, cnt, rank, E);
  k_scan1<<<nb, 256, 0, stream>>>(cnt, start, bsum, N);
  k_scan2<<<1, 256, 0, stream>>>(bsum, nb);
  k_scan3<<<nb, 256, 0, stream>>>(start, bsum, N);
  k_fill<<<gE, 256, 0, stream>>>(eattr, edge_emb, row, col, rank, start,
                                 srcs, wts, E);
  k_deg_csr<<<gN, 256, 0, stream>>>(start, wts, dinv, snorm, N);
  k_wts_csr<<<gN, 256, 0, stream>>>(start, srcs, dinv, wts, N);

  // ---- layer 1 ----
  k_gemm<128, 0, false><<<gGemm, 256, 0, stream>>>(x, W1, nullptr, bufA, N);
  k_agg_csr<<<gA, 256, 0, stream>>>(bufA, start, srcs, wts, snorm, b1, bufB, N);
  // ---- layer 2 (relu fused into GEMM input load) ----
  k_gemm<128, 0, true><<<gGemm, 256, 0, stream>>>(bufB, W2, nullptr, bufA, N);
  k_agg_csr<<<gA, 256, 0, stream>>>(bufA, start, srcs, wts, snorm, b2, bufB, N);
  // ---- layer 3 ----
  k_gemm<128, 0, true><<<gGemm, 256, 0, stream>>>(bufB, W3, nullptr, bufA, N);
  k_agg_csr<<<gA, 256, 0, stream>>>(bufA, start, srcs, wts, snorm, b3, bufB, N);

  // ---- classifier ----
  k_gemm<128, 1, true><<<gGemm, 256, 0, stream>>>(bufB, cW1, cb1, bufA, N);
  k_gemm<64, 2, false><<<gGemm, 256, 0, stream>>>(bufA, cW2, cb2, out, N);
}